// Round 8
// baseline (449.321 us; speedup 1.0000x reference)
//
#include <hip/hip_runtime.h>

#define BDIM 4
#define HDIM 16
#define SDIM 4096
#define DDIM 64
#define NBH (BDIM * HDIM)

#define NC 8                                // s-chunks for phase1
#define BH_STRIDE (DDIM * DDIM + DDIM)      // 4160 floats: [kv 64x64][kone 64]
#define CHUNK_FLOATS (NBH * BH_STRIDE)      // 266240 floats = 1,064,960 B

__device__ __forceinline__ float phi_f(float x) {
    // elu(x)+1 = x+1 (x>0) else exp(x)
    return x > 0.0f ? x + 1.0f : __expf(x);
}

// -------- Phase 1: kv[d][e] = sum_s phiK[s][d]*V[s][e]; kone[d] = sum_s phiK[s][d]
// Round-8 design: BOTH phiK and V staged in wave-PRIVATE single-buffered LDS
// tiles (16x64 each); 8x8 register tile per lane (full 64x64 per wave);
// zero barriers in the main loop (in-order DS within a wave: tile t+1's
// writes sit after tile t's reads in program order and alias -> compiler
// preserves order). Next-tile global loads issued between the two FMA
// half-tiles (~1000 VALU-cyc of cover). LDS 64 B / 64 FMA = 1.0 B/FMA ->
// LDS caps VALU at ~67% (vs 33% for the 4x4 round-0 design); V-from-LDS
// removes the latency wall of rounds 4/7 (V-from-global: 23-28% VALU).
// Cross-wave combine: r2's phased bufA/bufB epilogue (proven).
// LAUNCH-BOUNDS RULE (r1/4/5/6, measured): arch grant ~= 256/n:
// (256,2)->128-class OK; (256,4)->64 spills. Need ~110 => (256,2) only.
template<bool ATOMIC>
__global__ __launch_bounds__(256, 2) void la_phase1(
    const float* __restrict__ K, const float* __restrict__ V,
    const float* __restrict__ mask, float* __restrict__ outp, int chunk_rows)
{
    // main loop: wave w staging at smem + w*2048: [phiK 16x64][V 16x64]
    // epilogue overlay: [bufA 4160][bufB 4160][koneP 4x64]  (8576 floats)
    __shared__ __align__(16) float smem[8576];

    const int bh = blockIdx.y;
    const int b  = bh / HDIM;
    const int t  = threadIdx.x;
    const int w  = t >> 6;                  // wave 0..3
    const int l  = t & 63;
    const int rq = l >> 4;                  // staging row-in-quad 0..3
    const int c4 = (l & 15) << 2;           // staging col 0..60
    const int d0 = (l >> 3) << 3;           // compute: 8 d-rows
    const int e0 = (l & 7) << 3;            // compute: 8 e-cols

    float* kS = smem + w * 2048;            // wave-private [16][64]
    float* vS = kS + 1024;                  // wave-private [16][64]

    const float* Kb = K + (size_t)bh * SDIM * DDIM;
    const float* Vb = V + (size_t)bh * SDIM * DDIM;
    const float* mb = mask + (size_t)b * SDIM;
    const float scale = 0.35355339059327373f;   // 64^-0.25

    const int rows_per_wave = chunk_rows >> 2;
    const int s_wave = blockIdx.x * chunk_rows + w * rows_per_wave;
    const int ntiles = rows_per_wave >> 4;

    float acc[8][8] = {};
    float k1s[4] = {0.f, 0.f, 0.f, 0.f};    // kone partial, cols c4..c4+3

    // stage tile 0 (4 rows x float4 per lane, phi folded at staging)
    #pragma unroll
    for (int j = 0; j < 4; ++j) {
        const int s = s_wave + rq + (j << 2);
        const float4 kf = *(const float4*)(Kb + (size_t)s * DDIM + c4);
        const float4 vf = *(const float4*)(Vb + (size_t)s * DDIM + c4);
        const float  m  = mb[s];
        float4 p;
        p.x = phi_f(kf.x * scale) * m;
        p.y = phi_f(kf.y * scale) * m;
        p.z = phi_f(kf.z * scale) * m;
        p.w = phi_f(kf.w * scale) * m;
        k1s[0] += p.x; k1s[1] += p.y; k1s[2] += p.z; k1s[3] += p.w;
        *(float4*)&kS[(rq + (j << 2)) * DDIM + c4] = p;
        *(float4*)&vS[(rq + (j << 2)) * DDIM + c4] = vf;
    }

    #pragma unroll 1
    for (int tt = 0; tt < ntiles; ++tt) {
        // half A: ss 0..7 (reads tile tt; ordered after its staging writes)
        #pragma unroll
        for (int ss = 0; ss < 8; ++ss) {
            const float4 a0 = *(const float4*)&kS[ss * DDIM + d0];
            const float4 a1 = *(const float4*)&kS[ss * DDIM + d0 + 4];
            const float4 v0 = *(const float4*)&vS[ss * DDIM + e0];
            const float4 v1 = *(const float4*)&vS[ss * DDIM + e0 + 4];
            const float av[8] = {a0.x,a0.y,a0.z,a0.w,a1.x,a1.y,a1.z,a1.w};
            const float vv[8] = {v0.x,v0.y,v0.z,v0.w,v1.x,v1.y,v1.z,v1.w};
            #pragma unroll
            for (int i = 0; i < 8; ++i)
                #pragma unroll
                for (int j = 0; j < 8; ++j)
                    acc[i][j] += av[i] * vv[j];
        }
        // issue next tile's global loads: ~1000 VALU-cyc (half B) to retire
        const bool more = (tt + 1 < ntiles);
        float4 kf[4], vf[4]; float mm4[4];
        if (more) {
            #pragma unroll
            for (int j = 0; j < 4; ++j) {
                const int s = s_wave + ((tt + 1) << 4) + rq + (j << 2);
                kf[j]  = *(const float4*)(Kb + (size_t)s * DDIM + c4);
                vf[j]  = *(const float4*)(Vb + (size_t)s * DDIM + c4);
                mm4[j] = mb[s];
            }
        }
        // half B: ss 8..15
        #pragma unroll
        for (int ss = 8; ss < 16; ++ss) {
            const float4 a0 = *(const float4*)&kS[ss * DDIM + d0];
            const float4 a1 = *(const float4*)&kS[ss * DDIM + d0 + 4];
            const float4 v0 = *(const float4*)&vS[ss * DDIM + e0];
            const float4 v1 = *(const float4*)&vS[ss * DDIM + e0 + 4];
            const float av[8] = {a0.x,a0.y,a0.z,a0.w,a1.x,a1.y,a1.z,a1.w};
            const float vv[8] = {v0.x,v0.y,v0.z,v0.w,v1.x,v1.y,v1.z,v1.w};
            #pragma unroll
            for (int i = 0; i < 8; ++i)
                #pragma unroll
                for (int j = 0; j < 8; ++j)
                    acc[i][j] += av[i] * vv[j];
        }
        // stage tile tt+1 (writes after ALL reads of tt: in-order DS -> safe
        // with a single buffer, no fence, no barrier)
        if (more) {
            #pragma unroll
            for (int j = 0; j < 4; ++j) {
                float4 p;
                p.x = phi_f(kf[j].x * scale) * mm4[j];
                p.y = phi_f(kf[j].y * scale) * mm4[j];
                p.z = phi_f(kf[j].z * scale) * mm4[j];
                p.w = phi_f(kf[j].w * scale) * mm4[j];
                k1s[0] += p.x; k1s[1] += p.y; k1s[2] += p.z; k1s[3] += p.w;
                *(float4*)&kS[(rq + (j << 2)) * DDIM + c4] = p;
                *(float4*)&vS[(rq + (j << 2)) * DDIM + c4] = vf[j];
            }
        }
    }

    // kone: lanes {l, l^16, l^32, l^48} share c4 and cover the wave's rows
    #pragma unroll
    for (int i = 0; i < 4; ++i) {
        k1s[i] += __shfl_xor(k1s[i], 16);
        k1s[i] += __shfl_xor(k1s[i], 32);
    }

    // phased cross-wave acc reduction: waves {0,2}->bufA, {1,3}->bufB
    __syncthreads();
    float* bufA = smem;
    float* bufB = smem + 4160;
    float* koP  = smem + 8320;              // [4][64]
    if (l < 16) *(float4*)&koP[(w << 6) + c4] = make_float4(k1s[0], k1s[1], k1s[2], k1s[3]);
    if (w < 2) {
        float* Bp = w ? bufB : bufA;
        #pragma unroll
        for (int i = 0; i < 8; ++i) {
            *(float4*)&Bp[(d0 + i) * DDIM + e0]     = make_float4(acc[i][0], acc[i][1], acc[i][2], acc[i][3]);
            *(float4*)&Bp[(d0 + i) * DDIM + e0 + 4] = make_float4(acc[i][4], acc[i][5], acc[i][6], acc[i][7]);
        }
    }
    __syncthreads();
    if (w >= 2) {
        float* Bp = (w == 3) ? bufB : bufA;
        #pragma unroll
        for (int i = 0; i < 8; ++i) {
            float4 x0 = *(float4*)&Bp[(d0 + i) * DDIM + e0];
            float4 x1 = *(float4*)&Bp[(d0 + i) * DDIM + e0 + 4];
            x0.x += acc[i][0]; x0.y += acc[i][1]; x0.z += acc[i][2]; x0.w += acc[i][3];
            x1.x += acc[i][4]; x1.y += acc[i][5]; x1.z += acc[i][6]; x1.w += acc[i][7];
            *(float4*)&Bp[(d0 + i) * DDIM + e0]     = x0;
            *(float4*)&Bp[(d0 + i) * DDIM + e0 + 4] = x1;
        }
    }
    __syncthreads();

    float* base = ATOMIC ? (outp + (size_t)bh * BH_STRIDE)
                         : (outp + ((size_t)blockIdx.x * NBH + bh) * BH_STRIDE);
    // kv: 1024 float4 = 4 per thread
    #pragma unroll
    for (int k2 = 0; k2 < 4; ++k2) {
        const int g = t + 256 * k2;
        const float4 xa = ((const float4*)bufA)[g];
        const float4 xb = ((const float4*)bufB)[g];
        if (ATOMIC) {
            atomicAdd(&base[4*g + 0], xa.x + xb.x);
            atomicAdd(&base[4*g + 1], xa.y + xb.y);
            atomicAdd(&base[4*g + 2], xa.z + xb.z);
            atomicAdd(&base[4*g + 3], xa.w + xb.w);
        } else {
            *(float4*)&base[4*g] = make_float4(xa.x + xb.x, xa.y + xb.y, xa.z + xb.z, xa.w + xb.w);
        }
    }
    if (t < DDIM) {
        const float s1 = koP[t] + koP[64 + t] + koP[128 + t] + koP[192 + t];
        if (ATOMIC) atomicAdd(&base[DDIM * DDIM + t], s1);
        else        base[DDIM * DDIM + t] = s1;
    }
}

// -------- Reduce: fin[i] = sum_c part[c][i]; compile-time NC -> all loads in flight
template<int NCT>
__global__ __launch_bounds__(256) void la_reduce(
    const float* __restrict__ part, float* __restrict__ fin)
{
    const int g = blockIdx.x * 256 + threadIdx.x;     // float4 index
    const float4* p4 = (const float4*)part;
    float4 s = p4[g];
    #pragma unroll
    for (int c = 1; c < NCT; ++c) {
        const float4 v = p4[(size_t)c * (CHUNK_FLOATS / 4) + g];
        s.x += v.x; s.y += v.y; s.z += v.z; s.w += v.w;
    }
    ((float4*)fin)[g] = s;
}

// -------- Phase 2: out[s][e] = (sum_d phiQ[s][d]*kv[d][e]) * mm / (mm*sum_d phiQ[s][d]*kone[d] + 1e-8)
// Round-8: 8 rows x 8 cols per lane (wave covers 64 rows, block 256).
// phi(Q) staged per-dt in wave-private LDS laid out [dd][row] so the
// a-reads' bank index = row (2-way, free) -- the old [row][4] layout was a
// 4-way conflict. 256 B LDS / 288 FMA = 0.89 B/FMA -> ~70% VALU cap.
// Zero barriers in the dt loop (wave-private, in-order DS).
__global__ __launch_bounds__(256, 2) void la_phase2(
    const float* __restrict__ Q, const float* __restrict__ mask,
    const float* __restrict__ fin_all, float* __restrict__ out)
{
    __shared__ __align__(16) float kvL[DDIM * DDIM];   // 16 KB
    __shared__ __align__(16) float koL[DDIM];
    __shared__ __align__(16) float pq[4][2][4][64];    // 8 KB: [w][buf][dd][row]

    const int bh = blockIdx.y;
    const int b  = bh / HDIM;
    const int t  = threadIdx.x;
    const int w  = t >> 6;
    const int l  = t & 63;
    const int rg = l >> 3;                  // row group 0..7 (8 rows each)
    const int e0 = (l & 7) << 3;
    const int rbase = blockIdx.x * 256 + (w << 6);   // wave's 64 rows

    const float* fin = fin_all + (size_t)bh * BH_STRIDE;
    {
        const float4* src = (const float4*)fin;
        float4* dst = (float4*)kvL;
        #pragma unroll
        for (int k2 = 0; k2 < 4; ++k2) dst[t + 256 * k2] = src[t + 256 * k2];
        if (t < DDIM) koL[t] = fin[DDIM * DDIM + t];
    }

    const float* Qb   = Q + (size_t)bh * SDIM * DDIM;
    const float* mb   = mask + (size_t)b * SDIM;
    const float* Qrow = Qb + (size_t)(rbase + l) * DDIM;   // lane's own row
    const float scale = 0.35355339059327373f;

    // prologue loads overlap the kv-staging barrier
    float4 q0 = *(const float4*)(Qrow);      // dt=0
    float4 qn = *(const float4*)(Qrow + 4);  // dt=1
    __syncthreads();

    // stage dt=0 into buf 0 (wave-private; in-order DS suffices)
    {
        pq[w][0][0][l] = phi_f(q0.x * scale);
        pq[w][0][1][l] = phi_f(q0.y * scale);
        pq[w][0][2][l] = phi_f(q0.z * scale);
        pq[w][0][3][l] = phi_f(q0.w * scale);
    }

    float acc[8][8] = {};
    float nrm[8] = {0.f,0.f,0.f,0.f,0.f,0.f,0.f,0.f};

    #pragma unroll 1
    for (int dt = 0; dt < 16; ++dt) {
        const int d4  = dt << 2;
        const int cur = dt & 1;
        // stage next dt; prefetch dt+2's Q
        if (dt < 15) {
            pq[w][cur ^ 1][0][l] = phi_f(qn.x * scale);
            pq[w][cur ^ 1][1][l] = phi_f(qn.y * scale);
            pq[w][cur ^ 1][2][l] = phi_f(qn.z * scale);
            pq[w][cur ^ 1][3][l] = phi_f(qn.w * scale);
            if (dt < 14) qn = *(const float4*)(Qrow + ((dt + 2) << 2));
        }
        const float4 ko4 = *(const float4*)&koL[d4];
        #pragma unroll
        for (int dd = 0; dd < 4; ++dd) {
            const float4 af0 = *(const float4*)&pq[w][cur][dd][rg << 3];
            const float4 af1 = *(const float4*)&pq[w][cur][dd][(rg << 3) + 4];
            const float4 b0  = *(const float4*)&kvL[(d4 + dd) * DDIM + e0];
            const float4 b1  = *(const float4*)&kvL[(d4 + dd) * DDIM + e0 + 4];
            const float kod = (dd == 0) ? ko4.x : (dd == 1) ? ko4.y : (dd == 2) ? ko4.z : ko4.w;
            const float av[8] = {af0.x,af0.y,af0.z,af0.w,af1.x,af1.y,af1.z,af1.w};
            const float bv[8] = {b0.x,b0.y,b0.z,b0.w,b1.x,b1.y,b1.z,b1.w};
            #pragma unroll
            for (int i = 0; i < 8; ++i) {
                nrm[i] += av[i] * kod;
                #pragma unroll
                for (int j = 0; j < 8; ++j)
                    acc[i][j] += av[i] * bv[j];
            }
        }
    }

    // mask folds in exactly: out = mm*A / (mm*B + 1e-8)
    float* ob = out + (size_t)bh * SDIM * DDIM;
    #pragma unroll
    for (int i = 0; i < 8; ++i) {
        const int r  = rbase + (rg << 3) + i;
        const float mm  = mb[r];
        const float inv = mm / (mm * nrm[i] + 1e-8f);
        *(float4*)(ob + (size_t)r * DDIM + e0) =
            make_float4(acc[i][0] * inv, acc[i][1] * inv, acc[i][2] * inv, acc[i][3] * inv);
        *(float4*)(ob + (size_t)r * DDIM + e0 + 4) =
            make_float4(acc[i][4] * inv, acc[i][5] * inv, acc[i][6] * inv, acc[i][7] * inv);
    }
}

extern "C" void kernel_launch(void* const* d_in, const int* in_sizes, int n_in,
                              void* d_out, int out_size, void* d_ws, size_t ws_size,
                              hipStream_t stream) {
    const float* Q = (const float*)d_in[0];
    const float* K = (const float*)d_in[1];
    const float* V = (const float*)d_in[2];
    const float* M = (const float*)d_in[3];
    float* out = (float*)d_out;

    const size_t chunk_bytes = (size_t)CHUNK_FLOATS * sizeof(float);  // 1,064,960 B

    // ws_size is constant across calls -> same path every call (graph-safe)
    if (ws_size >= (size_t)(NC + 1) * chunk_bytes) {   // 9.6 MB: 8 partials + final
        float* part = (float*)d_ws;
        float* fin  = part + (size_t)NC * CHUNK_FLOATS;
        la_phase1<false><<<dim3(NC, NBH), dim3(256), 0, stream>>>(K, V, M, part, SDIM / NC);
        la_reduce<NC><<<dim3(CHUNK_FLOATS / 4 / 256), dim3(256), 0, stream>>>(part, fin);
        la_phase2<<<dim3(SDIM / 256, NBH), dim3(256), 0, stream>>>(Q, M, fin, out);
    } else {
        // fallback: atomic accumulation directly into final buffer (1.06 MB)
        float* fin = (float*)d_ws;
        hipMemsetAsync(d_ws, 0, chunk_bytes, stream);
        la_phase1<true><<<dim3(NC, NBH), dim3(256), 0, stream>>>(K, V, M, fin, SDIM / NC);
        la_phase2<<<dim3(SDIM / 256, NBH), dim3(256), 0, stream>>>(Q, M, fin, out);
    }
}